// Round 1
// baseline (4366.557 us; speedup 1.0000x reference)
//
#include <hip/hip_runtime.h>
#include <cstdint>

typedef _Float16 half_t;
typedef __attribute__((ext_vector_type(2))) _Float16 half2_t;
typedef __attribute__((ext_vector_type(8))) _Float16 half8_t;

#define B_    32
#define DIN   128
#define LEN   2048
#define DS    512
#define KREG  368                      // W_hh cols held in VGPRs (184 half2 regs)
#define KLDS  144                      // W_hh cols held in LDS
#define WSTRIDE 152                    // KLDS + 8 pad; 304 B = 19*16 (b128-aligned, odd-ish bank spread)
#define LDS_BYTES (DS * WSTRIDE * 2 + 2 * DS * 2)   // 155648 + 2048 = 157696 < 160 KiB

__device__ __forceinline__ float fast_tanh(float x) {
    float e = __expf(2.0f * x);        // large |x| saturates correctly via inf/0
    return 1.0f - 2.0f / (e + 1.0f);
}

// ---------------------------------------------------------------- kernel A
// pre[l][b][h] = sum_d x[b][d][l] * W_ih[h][d] + b_ih[h] + b_hh[h]   (f16 out)
__global__ __launch_bounds__(256) void rnn_pre_kernel(
    const float* __restrict__ x, const float* __restrict__ Wih,
    const float* __restrict__ bih, const float* __restrict__ bhh,
    half_t* __restrict__ pre)
{
    __shared__ float xl[DIN][16];
    const int t  = threadIdx.x;
    const int l0 = blockIdx.x * 16;
    const int b  = blockIdx.y;
#pragma unroll
    for (int i = 0; i < 8; ++i) {
        int idx = i * 256 + t;
        int d = idx >> 4, j = idx & 15;
        xl[d][j] = x[b * DIN * LEN + d * LEN + l0 + j];
    }
    __syncthreads();
    const int l  = t & 15;
    const int og = t >> 4;
    const int h0 = og * 32;
    float acc[32];
#pragma unroll
    for (int o = 0; o < 32; ++o) acc[o] = bih[h0 + o] + bhh[h0 + o];
    for (int dc = 0; dc < DIN; dc += 16) {
        float xv[16];
#pragma unroll
        for (int k = 0; k < 16; ++k) xv[k] = xl[dc + k][l];
#pragma unroll
        for (int o = 0; o < 32; ++o) {
            const float4* wr = (const float4*)(Wih + (h0 + o) * DIN + dc);
            float4 w0 = wr[0], w1 = wr[1], w2 = wr[2], w3 = wr[3];
            acc[o] += w0.x*xv[0]  + w0.y*xv[1]  + w0.z*xv[2]  + w0.w*xv[3]
                    + w1.x*xv[4]  + w1.y*xv[5]  + w1.z*xv[6]  + w1.w*xv[7]
                    + w2.x*xv[8]  + w2.y*xv[9]  + w2.z*xv[10] + w2.w*xv[11]
                    + w3.x*xv[12] + w3.y*xv[13] + w3.z*xv[14] + w3.w*xv[15];
        }
    }
    const int base = ((l0 + l) * B_ + b) * DS + h0;
#pragma unroll
    for (int g = 0; g < 4; ++g) {
        half8_t s8;
#pragma unroll
        for (int k = 0; k < 8; ++k) s8[k] = (half_t)acc[8 * g + k];
        *((half8_t*)(pre + base) + g) = s8;
    }
}

// ---------------------------------------------------------------- kernel B
// Sequential scan: one workgroup per batch, thread t owns row t of W_hh.
// W_hh row: cols [0,KREG) in VGPRs as f16 pairs, cols [KREG,512) in LDS.
// h ping-pongs in LDS (f16); pre prefetched distance-2; hs streamed to ws.
__global__ __launch_bounds__(512, 2) void rnn_recur_kernel(
    const float* __restrict__ Whh, const half_t* __restrict__ pre,
    half_t* __restrict__ hs)
{
    extern __shared__ char smem[];
    half_t* wlds = (half_t*)smem;                         // DS rows x WSTRIDE
    half_t* hb   = (half_t*)(smem + DS * WSTRIDE * 2);    // 2 x DS ping-pong
    const int t = threadIdx.x;
    const int b = blockIdx.x;

    // --- load my W row: reg part
    half2_t wr[KREG / 2];
    const float4* wrow4 = (const float4*)(Whh + t * DS);
#pragma unroll
    for (int i = 0; i < KREG / 4; ++i) {
        float4 v = wrow4[i];
        half2_t p0 = {(half_t)v.x, (half_t)v.y};
        half2_t p1 = {(half_t)v.z, (half_t)v.w};
        wr[2 * i]     = p0;
        wr[2 * i + 1] = p1;
    }
    // --- LDS part (cols KREG..511)
#pragma unroll
    for (int c = 0; c < KLDS / 8; ++c) {
        float4 u = wrow4[KREG / 4 + 2 * c];
        float4 v = wrow4[KREG / 4 + 2 * c + 1];
        half8_t w8 = {(half_t)u.x, (half_t)u.y, (half_t)u.z, (half_t)u.w,
                      (half_t)v.x, (half_t)v.y, (half_t)v.z, (half_t)v.w};
        *((half8_t*)(wlds + t * WSTRIDE) + c) = w8;
    }
    hb[t] = (half_t)0.0f;              // h_{-1} = 0 (buffer 0)
    __syncthreads();

    const int preIdx = b * DS + t;
    float p0f = (float)pre[preIdx];
    float p1f = (float)pre[B_ * DS + preIdx];
    const uint4* wl = (const uint4*)(wlds + t * WSTRIDE);

    int par = 0;
    for (int l = 0; l < LEN; ++l) {
        const int lp = (l + 2 < LEN) ? (l + 2) : (LEN - 1);
        half_t pn = pre[lp * (B_ * DS) + preIdx];          // prefetch
        const uint4* hc = (const uint4*)(hb + par * DS);
        float a0 = 0.f, a1 = 0.f, a2 = 0.f, a3 = 0.f;
        float a4 = 0.f, a5 = 0.f, a6 = 0.f, a7 = 0.f;
#pragma unroll
        for (int c = 0; c < KREG / 8; ++c) {               // 46 chunks
            uint4 hv = hc[c];                              // broadcast b128
            a0 = __builtin_amdgcn_fdot2(wr[4*c+0], __builtin_bit_cast(half2_t, hv.x), a0, false);
            a1 = __builtin_amdgcn_fdot2(wr[4*c+1], __builtin_bit_cast(half2_t, hv.y), a1, false);
            a2 = __builtin_amdgcn_fdot2(wr[4*c+2], __builtin_bit_cast(half2_t, hv.z), a2, false);
            a3 = __builtin_amdgcn_fdot2(wr[4*c+3], __builtin_bit_cast(half2_t, hv.w), a3, false);
        }
#pragma unroll
        for (int c = 0; c < KLDS / 8; ++c) {               // 18 chunks
            uint4 wv = wl[c];
            uint4 hv = hc[KREG / 8 + c];
            a4 = __builtin_amdgcn_fdot2(__builtin_bit_cast(half2_t, wv.x), __builtin_bit_cast(half2_t, hv.x), a4, false);
            a5 = __builtin_amdgcn_fdot2(__builtin_bit_cast(half2_t, wv.y), __builtin_bit_cast(half2_t, hv.y), a5, false);
            a6 = __builtin_amdgcn_fdot2(__builtin_bit_cast(half2_t, wv.z), __builtin_bit_cast(half2_t, hv.z), a6, false);
            a7 = __builtin_amdgcn_fdot2(__builtin_bit_cast(half2_t, wv.w), __builtin_bit_cast(half2_t, hv.w), a7, false);
        }
        float s  = ((a0 + a1) + (a2 + a3)) + ((a4 + a5) + (a6 + a7));
        float hn = fast_tanh(p0f + s);
        hs[l * (B_ * DS) + preIdx] = (half_t)hn;           // stream out (fire+forget)
        hb[(par ^ 1) * DS + t] = (half_t)hn;               // publish for next step
        p0f = p1f; p1f = (float)pn;
        par ^= 1;
        __syncthreads();                                   // one barrier/step (ping-pong safe)
    }
}

// ---------------------------------------------------------------- kernel C
// y[(l*B+b)*128 + o] = tanh(sum_s hs[l][b][s] * W_fc[o][s] + b_fc[o])
__global__ __launch_bounds__(256) void rnn_out_kernel(
    const half_t* __restrict__ hs, const float* __restrict__ Wfc,
    const float* __restrict__ bfc, float* __restrict__ y)
{
    __shared__ half_t hl[16][520];     // pad 512->520 breaks bank aliasing
    const int t  = threadIdx.x;
    const int l0 = blockIdx.x * 16;
    const int b  = blockIdx.y;
#pragma unroll
    for (int j = 0; j < 16; ++j) {
        *((uint32_t*)&hl[j][2 * t]) =
            *((const uint32_t*)hs + ((l0 + j) * B_ + b) * (DS / 2) + t);
    }
    __syncthreads();
    const int l  = t & 15;
    const int og = t >> 4;
    const int o0 = og * 8;
    float acc[8];
#pragma unroll
    for (int o = 0; o < 8; ++o) acc[o] = bfc[o0 + o];
    for (int sc = 0; sc < DS; sc += 16) {
        uint4 ha = *((const uint4*)&hl[l][sc]);
        uint4 hbv = *((const uint4*)&hl[l][sc + 8]);
        float xv[16];
        half2_t p;
        p = __builtin_bit_cast(half2_t, ha.x);  xv[0]  = (float)p[0]; xv[1]  = (float)p[1];
        p = __builtin_bit_cast(half2_t, ha.y);  xv[2]  = (float)p[0]; xv[3]  = (float)p[1];
        p = __builtin_bit_cast(half2_t, ha.z);  xv[4]  = (float)p[0]; xv[5]  = (float)p[1];
        p = __builtin_bit_cast(half2_t, ha.w);  xv[6]  = (float)p[0]; xv[7]  = (float)p[1];
        p = __builtin_bit_cast(half2_t, hbv.x); xv[8]  = (float)p[0]; xv[9]  = (float)p[1];
        p = __builtin_bit_cast(half2_t, hbv.y); xv[10] = (float)p[0]; xv[11] = (float)p[1];
        p = __builtin_bit_cast(half2_t, hbv.z); xv[12] = (float)p[0]; xv[13] = (float)p[1];
        p = __builtin_bit_cast(half2_t, hbv.w); xv[14] = (float)p[0]; xv[15] = (float)p[1];
#pragma unroll
        for (int o = 0; o < 8; ++o) {
            const float4* wr = (const float4*)(Wfc + (o0 + o) * DS + sc);
            float4 w0 = wr[0], w1 = wr[1], w2 = wr[2], w3 = wr[3];
            acc[o] += w0.x*xv[0]  + w0.y*xv[1]  + w0.z*xv[2]  + w0.w*xv[3]
                    + w1.x*xv[4]  + w1.y*xv[5]  + w1.z*xv[6]  + w1.w*xv[7]
                    + w2.x*xv[8]  + w2.y*xv[9]  + w2.z*xv[10] + w2.w*xv[11]
                    + w3.x*xv[12] + w3.y*xv[13] + w3.z*xv[14] + w3.w*xv[15];
        }
    }
    const int base = ((l0 + l) * B_ + b) * DIN + o0;
    float4 r0 = {fast_tanh(acc[0]), fast_tanh(acc[1]), fast_tanh(acc[2]), fast_tanh(acc[3])};
    float4 r1 = {fast_tanh(acc[4]), fast_tanh(acc[5]), fast_tanh(acc[6]), fast_tanh(acc[7])};
    *((float4*)(y + base))     = r0;
    *((float4*)(y + base) + 1) = r1;
}

// ---------------------------------------------------------------- launch
extern "C" void kernel_launch(void* const* d_in, const int* in_sizes, int n_in,
                              void* d_out, int out_size, void* d_ws, size_t ws_size,
                              hipStream_t stream) {
    (void)in_sizes; (void)n_in; (void)out_size; (void)ws_size;
    const float* x   = (const float*)d_in[0];
    const float* Wih = (const float*)d_in[1];
    const float* Whh = (const float*)d_in[2];
    const float* bih = (const float*)d_in[3];
    const float* bhh = (const float*)d_in[4];
    const float* Wfc = (const float*)d_in[5];
    const float* bfc = (const float*)d_in[6];
    float* y = (float*)d_out;

    half_t* pre = (half_t*)d_ws;                                        // 67,108,864 B
    half_t* hs  = (half_t*)((char*)d_ws + (size_t)LEN * B_ * DS * 2);   // 67,108,864 B

    hipFuncSetAttribute((const void*)rnn_recur_kernel,
                        hipFuncAttributeMaxDynamicSharedMemorySize, LDS_BYTES);

    rnn_pre_kernel<<<dim3(LEN / 16, B_), 256, 0, stream>>>(x, Wih, bih, bhh, pre);
    rnn_recur_kernel<<<dim3(B_), 512, LDS_BYTES, stream>>>(Whh, pre, hs);
    rnn_out_kernel<<<dim3(LEN / 16, B_), 256, 0, stream>>>(hs, Wfc, bfc, y);
}

// Round 2
// 3707.456 us; speedup vs baseline: 1.1778x; 1.1778x over previous
//
#include <hip/hip_runtime.h>
#include <cstdint>

typedef _Float16 half_t;
typedef __attribute__((ext_vector_type(2))) _Float16 half2_t;
typedef __attribute__((ext_vector_type(4))) _Float16 half4_t;
typedef __attribute__((ext_vector_type(8))) _Float16 half8_t;

#define B_    32
#define DIN   128
#define LEN   2048
#define DS    512
#define KREG  368                      // W_hh cols held in VGPRs (184 half2 regs)
#define KLDS  144                      // W_hh cols held in LDS
#define WSTRIDE 152                    // KLDS + 8 pad (304 B rows: 16B-aligned, 2-way-free banks)
#define LDS_BYTES (DS * WSTRIDE * 2 + 2 * DS * 2)   // 155648 + 2048 = 157696 < 160 KiB

__device__ __forceinline__ float fast_tanh(float x) {
    float e = __expf(2.0f * x);        // large |x| saturates correctly via inf/0
    return 1.0f - 2.0f / (e + 1.0f);
}

__device__ __forceinline__ float fd2(uint32_t a, uint32_t b, float c) {
    return __builtin_amdgcn_fdot2(__builtin_bit_cast(half2_t, a),
                                  __builtin_bit_cast(half2_t, b), c, false);
}

// ---------------------------------------------------------------- kernel A
// pre[b][l][h] = sum_d x[b][d][l]*W_ih[h][d] + b_ih[h] + b_hh[h]   (f16 out)
// LDS-tiled GEMM: M-tile = 64 l (fixed b), N-tile = 128 h, K = 128 (full).
__global__ __launch_bounds__(256) void rnn_pre_kernel(
    const float* __restrict__ x, const float* __restrict__ Wih,
    const float* __restrict__ bih, const float* __restrict__ bhh,
    half_t* __restrict__ pre)
{
    __shared__ half_t Xs[64 * 136];    // [l][d], stride 136
    __shared__ half_t Ws[128 * 136];   // [h][d], stride 136
    const int t  = threadIdx.x;
    const int l0 = blockIdx.x * 64;
    const int b  = blockIdx.y;
    const int h0 = blockIdx.z * 128;

    // Xs[j][d] = x[b][d][l0+j]  (coalesced in j)
#pragma unroll
    for (int i = 0; i < 32; ++i) {
        int idx = i * 256 + t;
        int j = idx & 63, d = idx >> 6;
        Xs[j * 136 + d] = (half_t)x[(size_t)b * DIN * LEN + (size_t)d * LEN + l0 + j];
    }
    // Ws[h][d] (float4 coalesced)
#pragma unroll
    for (int i = 0; i < 16; ++i) {
        int f4 = i * 256 + t;
        int h = f4 >> 5, d4 = f4 & 31;
        float4 w = *(const float4*)&Wih[(size_t)(h0 + h) * DIN + d4 * 4];
        half4_t hw = {(half_t)w.x, (half_t)w.y, (half_t)w.z, (half_t)w.w};
        *(half4_t*)&Ws[h * 136 + d4 * 4] = hw;
    }
    __syncthreads();

    const int lb = (t >> 4) * 4;       // 4 rows (l)
    const int hb = (t & 15) * 8;       // 8 cols (h)
    float acc[4][8];
#pragma unroll
    for (int i = 0; i < 4; ++i)
#pragma unroll
        for (int j = 0; j < 8; ++j) acc[i][j] = 0.f;

    for (int kc = 0; kc < DIN; kc += 8) {
        uint4 xa[4], wb[8];
#pragma unroll
        for (int i = 0; i < 4; ++i) xa[i] = *(const uint4*)&Xs[(lb + i) * 136 + kc];
#pragma unroll
        for (int j = 0; j < 8; ++j) wb[j] = *(const uint4*)&Ws[(hb + j) * 136 + kc];
#pragma unroll
        for (int i = 0; i < 4; ++i)
#pragma unroll
            for (int j = 0; j < 8; ++j) {
                float a = acc[i][j];
                a = fd2(xa[i].x, wb[j].x, a);
                a = fd2(xa[i].y, wb[j].y, a);
                a = fd2(xa[i].z, wb[j].z, a);
                a = fd2(xa[i].w, wb[j].w, a);
                acc[i][j] = a;
            }
    }

    float bias[8];
#pragma unroll
    for (int j = 0; j < 8; ++j) bias[j] = bih[h0 + hb + j] + bhh[h0 + hb + j];
#pragma unroll
    for (int i = 0; i < 4; ++i) {
        half8_t s;
#pragma unroll
        for (int j = 0; j < 8; ++j) s[j] = (half_t)(acc[i][j] + bias[j]);
        *(half8_t*)&pre[((size_t)b * LEN + l0 + lb + i) * DS + h0 + hb] = s;
    }
}

// ---------------------------------------------------------------- kernel B
// Sequential scan: one workgroup per batch, thread t owns row t of W_hh.
// W_hh row: cols [0,KREG) in VGPRs as f16 pairs, cols [KREG,512) in LDS.
// waves_per_eu(2,2): clamp occupancy -> 256-VGPR budget, no AGPR bounce.
__global__ __launch_bounds__(512) __attribute__((amdgpu_waves_per_eu(2, 2)))
void rnn_recur_kernel(
    const float* __restrict__ Whh, const half_t* __restrict__ pre,
    half_t* __restrict__ hs)
{
    extern __shared__ char smem[];
    half_t* wlds = (half_t*)smem;                         // DS rows x WSTRIDE
    half_t* hb   = (half_t*)(smem + DS * WSTRIDE * 2);    // 2 x DS ping-pong
    const int t = threadIdx.x;
    const int b = blockIdx.x;

    // --- load my W row: reg part
    half2_t wr[KREG / 2];
    const float4* wrow4 = (const float4*)(Whh + (size_t)t * DS);
#pragma unroll
    for (int i = 0; i < KREG / 4; ++i) {
        float4 v = wrow4[i];
        half2_t p0 = {(half_t)v.x, (half_t)v.y};
        half2_t p1 = {(half_t)v.z, (half_t)v.w};
        wr[2 * i]     = p0;
        wr[2 * i + 1] = p1;
    }
    // --- LDS part (cols KREG..511)
#pragma unroll
    for (int c = 0; c < KLDS / 8; ++c) {
        float4 u = wrow4[KREG / 4 + 2 * c];
        float4 v = wrow4[KREG / 4 + 2 * c + 1];
        half8_t w8 = {(half_t)u.x, (half_t)u.y, (half_t)u.z, (half_t)u.w,
                      (half_t)v.x, (half_t)v.y, (half_t)v.z, (half_t)v.w};
        *((half8_t*)(wlds + t * WSTRIDE) + c) = w8;
    }
    hb[t] = (half_t)0.0f;              // h_{-1} = 0 (buffer 0)
    __syncthreads();

    const half_t* pp = pre + (size_t)b * LEN * DS + t;   // pre[b][l][t]
    float p0f = (float)pp[0];
    float p1f = (float)pp[DS];
    const half_t* pp2 = pp + 2 * DS;
    half_t* hq = hs + (size_t)b * DS + t;                // hs[l][b][t]
    const uint4* wl = (const uint4*)(wlds + t * WSTRIDE);

    int par = 0;
    for (int l = 0; l < LEN; ++l) {
        half_t pn = *pp2;                                // prefetch (distance 2)
        if (l < LEN - 3) pp2 += DS;
        const uint4* hc = (const uint4*)(hb + par * DS);
        float a0 = 0.f, a1 = 0.f, a2 = 0.f, a3 = 0.f;
        float a4 = 0.f, a5 = 0.f, a6 = 0.f, a7 = 0.f;
#pragma unroll
        for (int c = 0; c < KREG / 8; ++c) {             // 46 chunks, broadcast b128
            uint4 hv = hc[c];
            a0 = __builtin_amdgcn_fdot2(wr[4*c+0], __builtin_bit_cast(half2_t, hv.x), a0, false);
            a1 = __builtin_amdgcn_fdot2(wr[4*c+1], __builtin_bit_cast(half2_t, hv.y), a1, false);
            a2 = __builtin_amdgcn_fdot2(wr[4*c+2], __builtin_bit_cast(half2_t, hv.z), a2, false);
            a3 = __builtin_amdgcn_fdot2(wr[4*c+3], __builtin_bit_cast(half2_t, hv.w), a3, false);
        }
#pragma unroll
        for (int c = 0; c < KLDS / 8; ++c) {             // 18 chunks
            uint4 wv = wl[c];
            uint4 hv = hc[KREG / 8 + c];
            a4 = fd2(wv.x, hv.x, a4);
            a5 = fd2(wv.y, hv.y, a5);
            a6 = fd2(wv.z, hv.z, a6);
            a7 = fd2(wv.w, hv.w, a7);
        }
        float s  = ((a0 + a1) + (a2 + a3)) + ((a4 + a5) + (a6 + a7));
        float hn = fast_tanh(p0f + s);
        half_t hh = (half_t)hn;
        hb[(par ^ 1) * DS + t] = hh;                     // publish for next step first
        *hq = hh;                                        // stream out (fire+forget)
        hq += B_ * DS;
        p0f = p1f; p1f = (float)pn;
        par ^= 1;
        __syncthreads();                                 // one barrier/step (ping-pong safe)
    }
}

// ---------------------------------------------------------------- kernel C
// y[r][o] = tanh(sum_s hs[r][s]*W_fc[o][s] + b_fc[o]),  r = l*B+b (flat order)
// LDS-tiled GEMM: M-tile = 64 r, N = 128 (all), K chunks of 64.
__global__ __launch_bounds__(256) void rnn_out_kernel(
    const half_t* __restrict__ hs, const float* __restrict__ Wfc,
    const float* __restrict__ bfc, float* __restrict__ y)
{
    __shared__ half_t Hs[64 * 72];     // [r][k], stride 72
    __shared__ half_t Ws[128 * 72];    // [o][k], stride 72
    const int t  = threadIdx.x;
    const int r0 = blockIdx.x * 64;

    const int lb = (t >> 4) * 4;       // 4 rows (r)
    const int ob = (t & 15) * 8;       // 8 cols (o)
    float acc[4][8];
#pragma unroll
    for (int i = 0; i < 4; ++i)
#pragma unroll
        for (int j = 0; j < 8; ++j) acc[i][j] = 0.f;

    for (int kc = 0; kc < DS; kc += 64) {
        // Hs[r][c] (uint4 coalesced; hs rows are contiguous f16)
#pragma unroll
        for (int i = 0; i < 2; ++i) {
            int u = i * 256 + t;
            int r = u >> 3, c8 = u & 7;
            uint4 v = ((const uint4*)(hs + (size_t)(r0 + r) * DS + kc))[c8];
            *(uint4*)&Hs[r * 72 + c8 * 8] = v;
        }
        // Ws[o][c] (float4 coalesced, cvt f16)
#pragma unroll
        for (int i = 0; i < 8; ++i) {
            int u = i * 256 + t;
            int o = u >> 4, c4 = u & 15;
            float4 w = *(const float4*)&Wfc[(size_t)o * DS + kc + c4 * 4];
            half4_t hw = {(half_t)w.x, (half_t)w.y, (half_t)w.z, (half_t)w.w};
            *(half4_t*)&Ws[o * 72 + c4 * 4] = hw;
        }
        __syncthreads();
#pragma unroll
        for (int k8 = 0; k8 < 64; k8 += 8) {
            uint4 xa[4], wb[8];
#pragma unroll
            for (int i = 0; i < 4; ++i) xa[i] = *(const uint4*)&Hs[(lb + i) * 72 + k8];
#pragma unroll
            for (int j = 0; j < 8; ++j) wb[j] = *(const uint4*)&Ws[(ob + j) * 72 + k8];
#pragma unroll
            for (int i = 0; i < 4; ++i)
#pragma unroll
                for (int j = 0; j < 8; ++j) {
                    float a = acc[i][j];
                    a = fd2(xa[i].x, wb[j].x, a);
                    a = fd2(xa[i].y, wb[j].y, a);
                    a = fd2(xa[i].z, wb[j].z, a);
                    a = fd2(xa[i].w, wb[j].w, a);
                    acc[i][j] = a;
                }
        }
        __syncthreads();
    }

#pragma unroll
    for (int i = 0; i < 4; ++i) {
        float4 r0v = {fast_tanh(acc[i][0] + bfc[ob + 0]), fast_tanh(acc[i][1] + bfc[ob + 1]),
                      fast_tanh(acc[i][2] + bfc[ob + 2]), fast_tanh(acc[i][3] + bfc[ob + 3])};
        float4 r1v = {fast_tanh(acc[i][4] + bfc[ob + 4]), fast_tanh(acc[i][5] + bfc[ob + 5]),
                      fast_tanh(acc[i][6] + bfc[ob + 6]), fast_tanh(acc[i][7] + bfc[ob + 7])};
        float* yr = y + (size_t)(r0 + lb + i) * DIN + ob;
        *(float4*)yr       = r0v;
        *((float4*)yr + 1) = r1v;
    }
}

// ---------------------------------------------------------------- launch
extern "C" void kernel_launch(void* const* d_in, const int* in_sizes, int n_in,
                              void* d_out, int out_size, void* d_ws, size_t ws_size,
                              hipStream_t stream) {
    (void)in_sizes; (void)n_in; (void)out_size; (void)ws_size;
    const float* x   = (const float*)d_in[0];
    const float* Wih = (const float*)d_in[1];
    const float* Whh = (const float*)d_in[2];
    const float* bih = (const float*)d_in[3];
    const float* bhh = (const float*)d_in[4];
    const float* Wfc = (const float*)d_in[5];
    const float* bfc = (const float*)d_in[6];
    float* y = (float*)d_out;

    half_t* pre = (half_t*)d_ws;                                        // pre[b][l][h]: 64 MB
    half_t* hs  = (half_t*)((char*)d_ws + (size_t)B_ * LEN * DS * 2);   // hs[l][b][s]: 64 MB

    hipFuncSetAttribute((const void*)rnn_recur_kernel,
                        hipFuncAttributeMaxDynamicSharedMemorySize, LDS_BYTES);

    rnn_pre_kernel<<<dim3(LEN / 64, B_, DS / 128), 256, 0, stream>>>(x, Wih, bih, bhh, pre);
    rnn_recur_kernel<<<dim3(B_), 512, LDS_BYTES, stream>>>(Whh, pre, hs);
    rnn_out_kernel<<<dim3(LEN * B_ / 64), 256, 0, stream>>>(hs, Wfc, bfc, y);
}

// Round 3
// 3369.331 us; speedup vs baseline: 1.2960x; 1.1004x over previous
//
#include <hip/hip_runtime.h>
#include <cstdint>

typedef _Float16 half_t;
typedef __attribute__((ext_vector_type(2))) _Float16 half2_t;
typedef __attribute__((ext_vector_type(4))) _Float16 half4_t;
typedef __attribute__((ext_vector_type(8))) _Float16 half8_t;
typedef __attribute__((ext_vector_type(4))) float f32x4;

#define B_    32
#define DIN   128
#define LEN   2048
#define DS    512
#define NKT   16                            // K-tiles of 32 (16x16x32 MFMA)
#define KTR   12                            // K-tiles resident in registers/AGPRs
#define KTL   (NKT - KTR)                   // K-tiles streamed from LDS
#define LDSB_BYTES (KTL * 32 * 1024)        // 4 kt x 32 ntiles x 1KB = 131072
#define HBUF_OFF   LDSB_BYTES
#define LDS_BYTES  (LDSB_BYTES + 2 * DS * 2)   // + h ping-pong = 133120 < 160K

__device__ __forceinline__ float fast_tanh(float x) {
    float e = __expf(2.0f * x);        // large |x| saturates correctly via inf/0
    return 1.0f - 2.0f / (e + 1.0f);
}

__device__ __forceinline__ float fd2(uint32_t a, uint32_t b, float c) {
    return __builtin_amdgcn_fdot2(__builtin_bit_cast(half2_t, a),
                                  __builtin_bit_cast(half2_t, b), c, false);
}

// B-fragment for 16x16x32: lane(c=lane&15, q=lane>>4) holds B[k0+q*8+j][n0+c]
// = W[n0+c][k0+q*8+j], j=0..7 -> 8 consecutive f32 from W row n0+c.
__device__ __forceinline__ half8_t load_wfrag(const float* __restrict__ W,
                                              int n0, int c, int q, int kt) {
    const float* p = W + (size_t)(n0 + c) * DS + kt * 32 + q * 8;
    float4 f0 = *(const float4*)p;
    float4 f1 = *(const float4*)(p + 4);
    half8_t r = {(half_t)f0.x, (half_t)f0.y, (half_t)f0.z, (half_t)f0.w,
                 (half_t)f1.x, (half_t)f1.y, (half_t)f1.z, (half_t)f1.w};
    return r;
}

// ---------------------------------------------------------------- kernel A
// pre[b][l][h] = sum_d x[b][d][l]*W_ih[h][d] + b_ih[h] + b_hh[h]   (f16 out)
__global__ __launch_bounds__(256) void rnn_pre_kernel(
    const float* __restrict__ x, const float* __restrict__ Wih,
    const float* __restrict__ bih, const float* __restrict__ bhh,
    half_t* __restrict__ pre)
{
    __shared__ half_t Xs[64 * 136];    // [l][d], stride 136
    __shared__ half_t Ws[128 * 136];   // [h][d], stride 136
    const int t  = threadIdx.x;
    const int l0 = blockIdx.x * 64;
    const int b  = blockIdx.y;
    const int h0 = blockIdx.z * 128;

#pragma unroll
    for (int i = 0; i < 32; ++i) {
        int idx = i * 256 + t;
        int j = idx & 63, d = idx >> 6;
        Xs[j * 136 + d] = (half_t)x[(size_t)b * DIN * LEN + (size_t)d * LEN + l0 + j];
    }
#pragma unroll
    for (int i = 0; i < 16; ++i) {
        int f4 = i * 256 + t;
        int h = f4 >> 5, d4 = f4 & 31;
        float4 w = *(const float4*)&Wih[(size_t)(h0 + h) * DIN + d4 * 4];
        half4_t hw = {(half_t)w.x, (half_t)w.y, (half_t)w.z, (half_t)w.w};
        *(half4_t*)&Ws[h * 136 + d4 * 4] = hw;
    }
    __syncthreads();

    const int lb = (t >> 4) * 4;
    const int hb = (t & 15) * 8;
    float acc[4][8];
#pragma unroll
    for (int i = 0; i < 4; ++i)
#pragma unroll
        for (int j = 0; j < 8; ++j) acc[i][j] = 0.f;

    for (int kc = 0; kc < DIN; kc += 8) {
        uint4 xa[4], wb[8];
#pragma unroll
        for (int i = 0; i < 4; ++i) xa[i] = *(const uint4*)&Xs[(lb + i) * 136 + kc];
#pragma unroll
        for (int j = 0; j < 8; ++j) wb[j] = *(const uint4*)&Ws[(hb + j) * 136 + kc];
#pragma unroll
        for (int i = 0; i < 4; ++i)
#pragma unroll
            for (int j = 0; j < 8; ++j) {
                float a = acc[i][j];
                a = fd2(xa[i].x, wb[j].x, a);
                a = fd2(xa[i].y, wb[j].y, a);
                a = fd2(xa[i].z, wb[j].z, a);
                a = fd2(xa[i].w, wb[j].w, a);
                acc[i][j] = a;
            }
    }

    float bias[8];
#pragma unroll
    for (int j = 0; j < 8; ++j) bias[j] = bih[h0 + hb + j] + bhh[h0 + hb + j];
#pragma unroll
    for (int i = 0; i < 4; ++i) {
        half8_t s;
#pragma unroll
        for (int j = 0; j < 8; ++j) s[j] = (half_t)(acc[i][j] + bias[j]);
        *(half8_t*)&pre[((size_t)b * LEN + l0 + lb + i) * DS + h0 + hb] = s;
    }
}

// ---------------------------------------------------------------- kernel B
// MFMA scan: one block per batch. Wave w owns outputs n in [w*64, w*64+64)
// as 4 16-wide N-tiles. h_t replicated across M via A-operand (M=1 real).
// W_hh B-fragments: kt 0..11 in regs/AGPRs, kt 12..15 in LDS (frag-linear).
__global__ __launch_bounds__(512) __attribute__((amdgpu_waves_per_eu(2, 2)))
void rnn_recur_kernel(
    const float* __restrict__ Whh, const half_t* __restrict__ pre,
    half_t* __restrict__ hs)
{
    extern __shared__ char smem[];
    const int t    = threadIdx.x;
    const int b    = blockIdx.x;
    const int w    = t >> 6;
    const int lane = t & 63;
    const int c    = lane & 15;
    const int q    = lane >> 4;
    const int n0w  = w * 64;

    // --- register-resident B-fragments (48 x half8 = 192 regs; MFMA-only use)
    half8_t breg[KTR][4];
#pragma unroll
    for (int kt = 0; kt < KTR; ++kt)
#pragma unroll
        for (int nt = 0; nt < 4; ++nt)
            breg[kt][nt] = load_wfrag(Whh, n0w + nt * 16, c, q, kt);

    // --- LDS-resident B-fragments, frag-linear: [(kt-KTR)*32+gid][lane*16B]
#pragma unroll
    for (int kt = KTR; kt < NKT; ++kt)
#pragma unroll
        for (int nt = 0; nt < 4; ++nt) {
            half8_t f = load_wfrag(Whh, n0w + nt * 16, c, q, kt);
            int gid = w * 4 + nt;
            *(half8_t*)(smem + (((kt - KTR) * 32 + gid) << 10) + lane * 16) = f;
        }
    if (t < DS) *(half_t*)(smem + HBUF_OFF + t * 2) = (half_t)0.f;  // h_{-1}=0
    __syncthreads();

    const half_t* prew = pre + (size_t)b * LEN * DS + n0w + lane;  // lane j -> n0w+j
    half_t* hsb = hs + (size_t)b * DS;
    float pv_cur = (float)prew[0];

    int par = 0;
    for (int l = 0; l < LEN; ++l) {
        int ln = (l + 1 < LEN) ? (l + 1) : (LEN - 1);
        float pv_nxt = (float)prew[(size_t)ln * DS];               // prefetch

        const char* hb = smem + HBUF_OFF + par * 1024;
        f32x4 acc0 = {0.f, 0.f, 0.f, 0.f};
        f32x4 acc1 = {0.f, 0.f, 0.f, 0.f};
        f32x4 acc2 = {0.f, 0.f, 0.f, 0.f};
        f32x4 acc3 = {0.f, 0.f, 0.f, 0.f};
#pragma unroll
        for (int kt = 0; kt < KTR; ++kt) {
            half8_t a = *(const half8_t*)(hb + kt * 64 + q * 16);  // 4-addr multicast
            acc0 = __builtin_amdgcn_mfma_f32_16x16x32_f16(a, breg[kt][0], acc0, 0, 0, 0);
            acc1 = __builtin_amdgcn_mfma_f32_16x16x32_f16(a, breg[kt][1], acc1, 0, 0, 0);
            acc2 = __builtin_amdgcn_mfma_f32_16x16x32_f16(a, breg[kt][2], acc2, 0, 0, 0);
            acc3 = __builtin_amdgcn_mfma_f32_16x16x32_f16(a, breg[kt][3], acc3, 0, 0, 0);
        }
#pragma unroll
        for (int kt = KTR; kt < NKT; ++kt) {
            half8_t a = *(const half8_t*)(hb + kt * 64 + q * 16);
            const char* bb = smem + (((kt - KTR) * 32 + w * 4) << 10) + lane * 16;
            half8_t b0 = *(const half8_t*)(bb);
            half8_t b1 = *(const half8_t*)(bb + 1024);
            half8_t b2 = *(const half8_t*)(bb + 2048);
            half8_t b3 = *(const half8_t*)(bb + 3072);
            acc0 = __builtin_amdgcn_mfma_f32_16x16x32_f16(a, b0, acc0, 0, 0, 0);
            acc1 = __builtin_amdgcn_mfma_f32_16x16x32_f16(a, b1, acc1, 0, 0, 0);
            acc2 = __builtin_amdgcn_mfma_f32_16x16x32_f16(a, b2, acc2, 0, 0, 0);
            acc3 = __builtin_amdgcn_mfma_f32_16x16x32_f16(a, b3, acc3, 0, 0, 0);
        }

        // pre value for tile nt at lane(c,q=0) was loaded by lane nt*16+c
        float p0 = __shfl(pv_cur, c +  0, 64);
        float p1 = __shfl(pv_cur, c + 16, 64);
        float p2 = __shfl(pv_cur, c + 32, 64);
        float p3 = __shfl(pv_cur, c + 48, 64);

        if (q == 0) {   // C/D layout: col=lane&15, row=(lane>>4)*4+reg; m=0 -> q==0, reg 0
            half_t h0 = (half_t)fast_tanh(p0 + acc0.x);
            half_t h1 = (half_t)fast_tanh(p1 + acc1.x);
            half_t h2 = (half_t)fast_tanh(p2 + acc2.x);
            half_t h3 = (half_t)fast_tanh(p3 + acc3.x);
            char* hn = smem + HBUF_OFF + (par ^ 1) * 1024;
            *(half_t*)(hn + (n0w +  0 + c) * 2) = h0;
            *(half_t*)(hn + (n0w + 16 + c) * 2) = h1;
            *(half_t*)(hn + (n0w + 32 + c) * 2) = h2;
            *(half_t*)(hn + (n0w + 48 + c) * 2) = h3;
            half_t* hrow = hsb + (size_t)l * (B_ * DS);            // hs[(l*B+b)*DS]
            hrow[n0w +  0 + c] = h0;
            hrow[n0w + 16 + c] = h1;
            hrow[n0w + 32 + c] = h2;
            hrow[n0w + 48 + c] = h3;
        }
        pv_cur = pv_nxt;
        par ^= 1;
        __syncthreads();
    }
}

// ---------------------------------------------------------------- kernel C
// y[r][o] = tanh(sum_s hs[r][s]*W_fc[o][s] + b_fc[o]),  r = l*B+b
__global__ __launch_bounds__(256) void rnn_out_kernel(
    const half_t* __restrict__ hs, const float* __restrict__ Wfc,
    const float* __restrict__ bfc, float* __restrict__ y)
{
    __shared__ half_t Hs[64 * 72];     // [r][k], stride 72
    __shared__ half_t Ws[128 * 72];    // [o][k], stride 72
    const int t  = threadIdx.x;
    const int r0 = blockIdx.x * 64;

    const int lb = (t >> 4) * 4;
    const int ob = (t & 15) * 8;
    float acc[4][8];
#pragma unroll
    for (int i = 0; i < 4; ++i)
#pragma unroll
        for (int j = 0; j < 8; ++j) acc[i][j] = 0.f;

    for (int kc = 0; kc < DS; kc += 64) {
#pragma unroll
        for (int i = 0; i < 2; ++i) {
            int u = i * 256 + t;
            int r = u >> 3, c8 = u & 7;
            uint4 v = ((const uint4*)(hs + (size_t)(r0 + r) * DS + kc))[c8];
            *(uint4*)&Hs[r * 72 + c8 * 8] = v;
        }
#pragma unroll
        for (int i = 0; i < 8; ++i) {
            int u = i * 256 + t;
            int o = u >> 4, c4 = u & 15;
            float4 wv = *(const float4*)&Wfc[(size_t)o * DS + kc + c4 * 4];
            half4_t hw = {(half_t)wv.x, (half_t)wv.y, (half_t)wv.z, (half_t)wv.w};
            *(half4_t*)&Ws[o * 72 + c4 * 4] = hw;
        }
        __syncthreads();
#pragma unroll
        for (int k8 = 0; k8 < 64; k8 += 8) {
            uint4 xa[4], wb[8];
#pragma unroll
            for (int i = 0; i < 4; ++i) xa[i] = *(const uint4*)&Hs[(lb + i) * 72 + k8];
#pragma unroll
            for (int j = 0; j < 8; ++j) wb[j] = *(const uint4*)&Ws[(ob + j) * 72 + k8];
#pragma unroll
            for (int i = 0; i < 4; ++i)
#pragma unroll
                for (int j = 0; j < 8; ++j) {
                    float a = acc[i][j];
                    a = fd2(xa[i].x, wb[j].x, a);
                    a = fd2(xa[i].y, wb[j].y, a);
                    a = fd2(xa[i].z, wb[j].z, a);
                    a = fd2(xa[i].w, wb[j].w, a);
                    acc[i][j] = a;
                }
        }
        __syncthreads();
    }

#pragma unroll
    for (int i = 0; i < 4; ++i) {
        float4 r0v = {fast_tanh(acc[i][0] + bfc[ob + 0]), fast_tanh(acc[i][1] + bfc[ob + 1]),
                      fast_tanh(acc[i][2] + bfc[ob + 2]), fast_tanh(acc[i][3] + bfc[ob + 3])};
        float4 r1v = {fast_tanh(acc[i][4] + bfc[ob + 4]), fast_tanh(acc[i][5] + bfc[ob + 5]),
                      fast_tanh(acc[i][6] + bfc[ob + 6]), fast_tanh(acc[i][7] + bfc[ob + 7])};
        float* yr = y + (size_t)(r0 + lb + i) * DIN + ob;
        *(float4*)yr       = r0v;
        *((float4*)yr + 1) = r1v;
    }
}

// ---------------------------------------------------------------- launch
extern "C" void kernel_launch(void* const* d_in, const int* in_sizes, int n_in,
                              void* d_out, int out_size, void* d_ws, size_t ws_size,
                              hipStream_t stream) {
    (void)in_sizes; (void)n_in; (void)out_size; (void)ws_size;
    const float* x   = (const float*)d_in[0];
    const float* Wih = (const float*)d_in[1];
    const float* Whh = (const float*)d_in[2];
    const float* bih = (const float*)d_in[3];
    const float* bhh = (const float*)d_in[4];
    const float* Wfc = (const float*)d_in[5];
    const float* bfc = (const float*)d_in[6];
    float* y = (float*)d_out;

    half_t* pre = (half_t*)d_ws;                                        // pre[b][l][h]: 64 MB
    half_t* hs  = (half_t*)((char*)d_ws + (size_t)B_ * LEN * DS * 2);   // hs[(l*B+b)][s]: 64 MB

    hipFuncSetAttribute((const void*)rnn_recur_kernel,
                        hipFuncAttributeMaxDynamicSharedMemorySize, LDS_BYTES);

    rnn_pre_kernel<<<dim3(LEN / 64, B_, DS / 128), 256, 0, stream>>>(x, Wih, bih, bhh, pre);
    rnn_recur_kernel<<<dim3(B_), 512, LDS_BYTES, stream>>>(Whh, pre, hs);
    rnn_out_kernel<<<dim3(LEN * B_ / 64), 256, 0, stream>>>(hs, Wfc, bfc, y);
}